// Round 5
// baseline (234.535 us; speedup 1.0000x reference)
//
#include <hip/hip_runtime.h>
#include <hip/hip_cooperative_groups.h>

namespace cg = cooperative_groups;

static constexpr int N_NODES = 250000;
static constexpr int N_EDGES = 5000000;

// ---- fast path: counting-sort by dst>>9 into 512-node buckets ----
static constexpr int NB    = 512;                       // partition blocks
static constexpr int CHUNK = 9768;                      // per-block edges, mult of 4; NB*CHUNK >= N_EDGES
static constexpr int NBK   = 512;                       // bucket slots (dst>>9); 489 used
static constexpr int NBUCK = (N_NODES + 511) / 512;     // 489 consumer blocks
static constexpr int CAP   = 32;                        // LDS staging slots per bucket (k_part)
static constexpr int TILE  = 4096;                      // edges per k_part block-tile
static constexpr int CAPE  = 12288;                     // LDS edge cache per bucket (mean 10224, +20 sigma)

// pack: bits 0..17 = src (N < 2^18), bits 20..28 = dst & 511
__device__ __forceinline__ unsigned pack_edge(unsigned s, unsigned d) {
    return s | ((d & 511u) << 20);
}

__global__ void k_hist(const int* __restrict__ dst, unsigned* __restrict__ hist) {
    __shared__ unsigned h[NBK];
    for (int j = threadIdx.x; j < NBK; j += 512) h[j] = 0;
    __syncthreads();
    int beg = blockIdx.x * CHUNK;
    int end = min(beg + CHUNK, N_EDGES);
    for (int e = beg + (int)threadIdx.x * 4; e < end; e += 2048) {
        if (e + 4 <= end) {
            int4 d4 = *(const int4*)(dst + e);
            atomicAdd(&h[((unsigned)d4.x) >> 9], 1u);
            atomicAdd(&h[((unsigned)d4.y) >> 9], 1u);
            atomicAdd(&h[((unsigned)d4.z) >> 9], 1u);
            atomicAdd(&h[((unsigned)d4.w) >> 9], 1u);
        } else {
            for (int j = 0; j < 4 && e + j < end; ++j)
                atomicAdd(&h[((unsigned)dst[e + j]) >> 9], 1u);
        }
    }
    __syncthreads();
    unsigned* o = hist + (size_t)blockIdx.x * NBK;
    for (int j = threadIdx.x; j < NBK; j += 512) o[j] = h[j];
}

__global__ void k_total(const unsigned* __restrict__ hist, unsigned* __restrict__ total) {
    int b = blockIdx.x * 256 + threadIdx.x;
    if (b >= NBK) return;
    unsigned s = 0;
    for (int i = 0; i < NB; ++i) s += hist[(size_t)i * NBK + b];
    total[b] = s;
}

__global__ void k_scanbase(const unsigned* __restrict__ total, unsigned* __restrict__ base) {
    __shared__ unsigned sh[NBK];
    int t = threadIdx.x;
    unsigned v = total[t];
    sh[t] = v;
    __syncthreads();
    for (int off = 1; off < NBK; off <<= 1) {
        unsigned x = 0;
        if (t >= off) x = sh[t - off];
        __syncthreads();
        sh[t] += x;
        __syncthreads();
    }
    base[t] = sh[t] - v;   // exclusive scan
}

__global__ void k_off(unsigned* __restrict__ hist, const unsigned* __restrict__ base) {
    int b = blockIdx.x * 256 + threadIdx.x;
    if (b >= NBK) return;
    unsigned run = base[b];
    for (int i = 0; i < NB; ++i) {
        size_t idx = (size_t)i * NBK + b;
        unsigned v = hist[idx];
        hist[idx] = run;    // hist becomes per-(block,bucket) scatter cursor base
        run += v;
    }
}

// Partition: LDS-staged, XOR-swizzled bins, coalesced 16-word flushes.
__global__ void __launch_bounds__(512, 4)
k_part(const int* __restrict__ src, const int* __restrict__ dst,
       const unsigned* __restrict__ off, unsigned* __restrict__ part) {
    __shared__ unsigned stage[NBK][CAP];   // 64 KB, swizzled: slot = pos ^ (b&31)
    __shared__ unsigned cnt[NBK];
    __shared__ unsigned goff[NBK];
    const unsigned* o = off + (size_t)blockIdx.x * NBK;
    for (int j = threadIdx.x; j < NBK; j += 512) { goff[j] = o[j]; cnt[j] = 0; }
    __syncthreads();
    int beg = blockIdx.x * CHUNK;
    int end = min(beg + CHUNK, N_EDGES);
    const int g  = threadIdx.x >> 4;   // 32 flush groups of 16 lanes
    const int gl = threadIdx.x & 15;
    for (int tb = beg; tb < end; tb += TILE) {
        int te = min(tb + TILE, end);
        // phase 1: stage into LDS bins (two vectorized half-steps per tile)
        for (int half = tb; half < te; half += 2048) {
            int he = min(half + 2048, te);
            int e = half + (int)threadIdx.x * 4;
            int s0, s1, s2, s3, d0, d1, d2, d3, cnt4 = 0;
            if (e + 4 <= he) {
                int4 d4 = *(const int4*)(dst + e);
                int4 s4 = *(const int4*)(src + e);
                d0 = d4.x; d1 = d4.y; d2 = d4.z; d3 = d4.w;
                s0 = s4.x; s1 = s4.y; s2 = s4.z; s3 = s4.w;
                cnt4 = 4;
            } else {
                int m = he - e;
                cnt4 = m < 0 ? 0 : m;
                if (cnt4 > 0) { d0 = dst[e];     s0 = src[e]; }
                if (cnt4 > 1) { d1 = dst[e + 1]; s1 = src[e + 1]; }
                if (cnt4 > 2) { d2 = dst[e + 2]; s2 = src[e + 2]; }
                if (cnt4 > 3) { d3 = dst[e + 3]; s3 = src[e + 3]; }
            }
            #pragma unroll
            for (int j = 0; j < 4; ++j) {
                if (j >= cnt4) break;
                int dd = j == 0 ? d0 : j == 1 ? d1 : j == 2 ? d2 : d3;
                int ss = j == 0 ? s0 : j == 1 ? s1 : j == 2 ? s2 : s3;
                unsigned b = ((unsigned)dd) >> 9;
                unsigned v = pack_edge((unsigned)ss, (unsigned)dd);
                unsigned pos = atomicAdd(&cnt[b], 1u);
                if (pos < CAP) stage[b][pos ^ (b & 31u)] = v;
                else part[atomicAdd(&goff[b], 1u)] = v;   // rare overflow
            }
        }
        __syncthreads();
        const bool last = (te == end);
        // phase 2: coalesced flush of full 16-groups (residual carried across tiles)
        for (int b = g; b < NBK; b += 32) {
            const unsigned c = (unsigned)b & 31u;
            unsigned n = min(cnt[b], (unsigned)CAP);
            unsigned nfull = n >> 4, rem = n & 15u;
            unsigned gbase = goff[b];
            for (unsigned k = 0; k < nfull; ++k)
                part[gbase + k * 16u + gl] = stage[b][(k * 16u + gl) ^ c];
            if (last) {
                if (gl < rem) part[gbase + nfull * 16u + gl] = stage[b][(nfull * 16u + gl) ^ c];
            } else {
                if (gl < rem) {
                    unsigned tmp = stage[b][(nfull * 16u + gl) ^ c];
                    stage[b][(unsigned)gl ^ c] = tmp;   // disjoint halves when nfull>0; same-slot no-op when nfull==0
                }
            }
            if (gl == 0) {
                goff[b] = gbase + (last ? n : nfull * 16u);
                cnt[b]  = last ? 0u : rem;
            }
        }
        __syncthreads();
    }
}

// Fused consumer: deg+dinv+xs -> grid.sync -> agg1+MLP -> grid.sync -> agg2.
// Bucket's edges cached in LDS on first pass; di and partial out live in registers.
__global__ void __launch_bounds__(512, 4)
k_consume(const unsigned* __restrict__ part,
          const unsigned* __restrict__ base, const unsigned* __restrict__ total,
          const float* __restrict__ x,
          const float* __restrict__ W1, const float* __restrict__ b1,
          const float* __restrict__ W2, const float* __restrict__ b2,
          float* __restrict__ xs, float* __restrict__ u, float* __restrict__ out) {
    __shared__ unsigned eL[CAPE];     // 48 KB edge cache
    __shared__ unsigned cnt[512];
    __shared__ float acc[512];
    cg::grid_group grid = cg::this_grid();
    const unsigned tid = threadIdx.x;
    const int bid = blockIdx.x;
    const unsigned st = base[bid], tot = total[bid];
    const unsigned en = st + tot;

    cnt[tid] = 0;
    __syncthreads();

    // ---- phase 1: degree count + LDS-cache the bucket's edges ----
    {
        unsigned a0 = (st + 3u) & ~3u; if (a0 > en) a0 = en;
        unsigned a1 = en & ~3u;        if (a1 < a0) a1 = a0;
        if (st + tid < a0) {
            unsigned p = part[st + tid];
            atomicAdd(&cnt[(p >> 20) & 511u], 1u);
            if (tid < CAPE) eL[tid] = p;
        }
        for (unsigned gk = a0 + tid * 4u; gk < a1; gk += 2048u) {
            uint4 q = *(const uint4*)(part + gk);
            unsigned k = gk - st;
            atomicAdd(&cnt[(q.x >> 20) & 511u], 1u);
            atomicAdd(&cnt[(q.y >> 20) & 511u], 1u);
            atomicAdd(&cnt[(q.z >> 20) & 511u], 1u);
            atomicAdd(&cnt[(q.w >> 20) & 511u], 1u);
            if (k + 3 < CAPE) {
                eL[k] = q.x; eL[k + 1] = q.y; eL[k + 2] = q.z; eL[k + 3] = q.w;
            } else {
                if (k < CAPE)     eL[k]     = q.x;
                if (k + 1 < CAPE) eL[k + 1] = q.y;
                if (k + 2 < CAPE) eL[k + 2] = q.z;
                if (k + 3 < CAPE) eL[k + 3] = q.w;
            }
        }
        if (a1 + tid < en) {
            unsigned p = part[a1 + tid];
            unsigned k = a1 + tid - st;
            atomicAdd(&cnt[(p >> 20) & 511u], 1u);
            if (k < CAPE) eL[k] = p;
        }
    }
    __syncthreads();
    const int n = bid * 512 + (int)tid;
    float di = 0.f, xsv = 0.f;
    if (n < N_NODES) {
        di = rsqrtf((float)cnt[tid] + 1.0f);   // +1 self-loop
        xsv = x[n] * di;
        xs[n] = xsv;
    }
    acc[tid] = 0.f;
    grid.sync();   // xs visible to all buckets

    // ---- phase 2: layer-1 aggregate + fused MLP ----
    #pragma unroll 4
    for (unsigned k = tid; k < tot; k += 512u) {
        unsigned p = (k < CAPE) ? eL[k] : part[st + k];
        atomicAdd(&acc[(p >> 20) & 511u], xs[p & 0x3FFFFu]);
    }
    __syncthreads();
    float o = 0.f;
    if (n < N_NODES) {
        float sv = di * (acc[tid] + xsv);
        float t = 0.f;
        #pragma unroll
        for (int kk = 0; kk < 16; ++kk)
            t = fmaf(fmaxf(fmaf(sv, W1[kk], b1[kk]), 0.f), W2[kk], t);
        u[n] = t * di;
        o = b2[0] + t * di * di;   // bias + layer-2 self-loop, carried in register
    }
    acc[tid] = 0.f;   // safe: only this thread read acc[tid] above
    grid.sync();      // u visible to all buckets

    // ---- phase 3: layer-2 aggregate ----
    #pragma unroll 4
    for (unsigned k = tid; k < tot; k += 512u) {
        unsigned p = (k < CAPE) ? eL[k] : part[st + k];
        atomicAdd(&acc[(p >> 20) & 511u], u[p & 0x3FFFFu]);
    }
    __syncthreads();
    if (n < N_NODES) out[n] = o + di * acc[tid];
}

// ---- fallback path (device atomics) if ws is too small ----
__global__ void f_init(float* __restrict__ deg) {
    int n = blockIdx.x * blockDim.x + threadIdx.x;
    if (n < N_NODES) deg[n] = 1.0f;
}
__global__ void f_deg(const int* __restrict__ dst, float* __restrict__ deg) {
    int e = blockIdx.x * blockDim.x + threadIdx.x;
    if (e < N_EDGES) atomicAdd(&deg[dst[e]], 1.0f);
}
__global__ void f_node1(const float* __restrict__ x, const float* __restrict__ deg,
                        float* __restrict__ dinv, float* __restrict__ xs,
                        float* __restrict__ s) {
    int n = blockIdx.x * blockDim.x + threadIdx.x;
    if (n < N_NODES) {
        float di = rsqrtf(deg[n]);
        float xv = x[n];
        dinv[n] = di; xs[n] = xv * di; s[n] = xv * di * di;
    }
}
__global__ void f_sc1(const int* __restrict__ src, const int* __restrict__ dst,
                      const float* __restrict__ xs, const float* __restrict__ dinv,
                      float* __restrict__ s) {
    int e = blockIdx.x * blockDim.x + threadIdx.x;
    if (e < N_EDGES) atomicAdd(&s[dst[e]], xs[src[e]] * dinv[dst[e]]);
}
__global__ void f_node2(const float* __restrict__ s, const float* __restrict__ dinv,
                        const float* __restrict__ W1, const float* __restrict__ b1,
                        const float* __restrict__ W2, const float* __restrict__ b2,
                        float* __restrict__ u, float* __restrict__ out) {
    int n = blockIdx.x * blockDim.x + threadIdx.x;
    if (n < N_NODES) {
        float sv = s[n], acc = 0.0f;
        #pragma unroll
        for (int k = 0; k < 16; ++k)
            acc = fmaf(fmaxf(fmaf(sv, W1[k], b1[k]), 0.f), W2[k], acc);
        float di = dinv[n];
        u[n] = acc * di; out[n] = b2[0] + acc * di * di;
    }
}
__global__ void f_sc2(const int* __restrict__ src, const int* __restrict__ dst,
                      const float* __restrict__ u, const float* __restrict__ dinv,
                      float* __restrict__ out) {
    int e = blockIdx.x * blockDim.x + threadIdx.x;
    if (e < N_EDGES) atomicAdd(&out[dst[e]], u[src[e]] * dinv[dst[e]]);
}

extern "C" void kernel_launch(void* const* d_in, const int* in_sizes, int n_in,
                              void* d_out, int out_size, void* d_ws, size_t ws_size,
                              hipStream_t stream) {
    const float* x  = (const float*)d_in[0];
    const int*   ei = (const int*)d_in[1];
    const float* W1 = (const float*)d_in[2];
    const float* b1 = (const float*)d_in[3];
    const float* W2 = (const float*)d_in[4];
    const float* b2 = (const float*)d_in[5];
    float* out = (float*)d_out;
    const int* src = ei;
    const int* dst = ei + N_EDGES;

    const size_t need = ((size_t)NB * NBK + 2 * NBK + N_EDGES + 2 * N_NODES) * 4;

    if (ws_size >= need) {
        unsigned* hist  = (unsigned*)d_ws;
        unsigned* total = hist + (size_t)NB * NBK;
        unsigned* base  = total + NBK;
        unsigned* part  = base + NBK;
        float* xs = (float*)(part + N_EDGES);
        float* u  = xs + N_NODES;

        k_hist    <<<NB, 512, 0, stream>>>(dst, hist);
        k_total   <<<NBK / 256, 256, 0, stream>>>(hist, total);
        k_scanbase<<<1, NBK, 0, stream>>>(total, base);
        k_off     <<<NBK / 256, 256, 0, stream>>>(hist, base);
        k_part    <<<NB, 512, 0, stream>>>(src, dst, hist, part);

        const unsigned* cpart  = part;
        const unsigned* cbase  = base;
        const unsigned* ctotal = total;
        void* args[] = { (void*)&cpart, (void*)&cbase, (void*)&ctotal, (void*)&x,
                         (void*)&W1, (void*)&b1, (void*)&W2, (void*)&b2,
                         (void*)&xs, (void*)&u, (void*)&out };
        hipLaunchCooperativeKernel((void*)k_consume, dim3(NBUCK), dim3(512),
                                   args, 0, stream);
    } else {
        float* deg  = (float*)d_ws;
        float* dinv = deg + N_NODES;
        float* xs   = dinv + N_NODES;
        float* s    = xs + N_NODES;
        float* u    = deg;
        const int TB = 256;
        const int gn = (N_NODES + TB - 1) / TB;
        const int ge = (N_EDGES + TB - 1) / TB;
        f_init <<<gn, TB, 0, stream>>>(deg);
        f_deg  <<<ge, TB, 0, stream>>>(dst, deg);
        f_node1<<<gn, TB, 0, stream>>>(x, deg, dinv, xs, s);
        f_sc1  <<<ge, TB, 0, stream>>>(src, dst, xs, dinv, s);
        f_node2<<<gn, TB, 0, stream>>>(s, dinv, W1, b1, W2, b2, u, out);
        f_sc2  <<<ge, TB, 0, stream>>>(src, dst, u, dinv, out);
    }
}

// Round 6
// 132.709 us; speedup vs baseline: 1.7673x; 1.7673x over previous
//
#include <hip/hip_runtime.h>

static constexpr int N_NODES = 250000;
static constexpr int N_EDGES = 5000000;

// ---- counting-sort by dst>>8 into 256-node buckets ----
static constexpr int NB    = 512;                       // partition blocks
static constexpr int CHUNK = 9768;                      // per-block edges, mult of 4; NB*CHUNK >= N_EDGES
static constexpr int NBK   = 1024;                      // bucket slots (dst>>8); 977 used
static constexpr int NBUCK = (N_NODES + 255) / 256;     // 977 consumer blocks
static constexpr int CAP   = 16;                        // LDS staging slots per bucket (k_part)
static constexpr int TILE  = 4096;                      // edges per k_part block-tile

// pack: bits 0..17 = src (N < 2^18), bits 20..27 = dst & 255
__device__ __forceinline__ unsigned pack_edge(unsigned s, unsigned d) {
    return s | ((d & 255u) << 20);
}

__global__ void k_hist(const int* __restrict__ dst, unsigned* __restrict__ hist) {
    __shared__ unsigned h[NBK];
    for (int j = threadIdx.x; j < NBK; j += 512) h[j] = 0;
    __syncthreads();
    int beg = blockIdx.x * CHUNK;
    int end = min(beg + CHUNK, N_EDGES);
    for (int e = beg + (int)threadIdx.x * 4; e < end; e += 2048) {
        if (e + 4 <= end) {
            int4 d4 = *(const int4*)(dst + e);
            atomicAdd(&h[((unsigned)d4.x) >> 8], 1u);
            atomicAdd(&h[((unsigned)d4.y) >> 8], 1u);
            atomicAdd(&h[((unsigned)d4.z) >> 8], 1u);
            atomicAdd(&h[((unsigned)d4.w) >> 8], 1u);
        } else {
            for (int j = 0; j < 4 && e + j < end; ++j)
                atomicAdd(&h[((unsigned)dst[e + j]) >> 8], 1u);
        }
    }
    __syncthreads();
    unsigned* o = hist + (size_t)blockIdx.x * NBK;
    for (int j = threadIdx.x; j < NBK; j += 512) o[j] = h[j];
}

__global__ void k_total(const unsigned* __restrict__ hist, unsigned* __restrict__ total) {
    int b = blockIdx.x * 256 + threadIdx.x;
    if (b >= NBK) return;
    unsigned s = 0;
    for (int i = 0; i < NB; ++i) s += hist[(size_t)i * NBK + b];
    total[b] = s;
}

__global__ void k_scanbase(const unsigned* __restrict__ total, unsigned* __restrict__ base) {
    __shared__ unsigned sh[NBK];
    int t = threadIdx.x;
    unsigned v = total[t];
    sh[t] = v;
    __syncthreads();
    for (int off = 1; off < NBK; off <<= 1) {
        unsigned x = 0;
        if (t >= off) x = sh[t - off];
        __syncthreads();
        sh[t] += x;
        __syncthreads();
    }
    base[t] = sh[t] - v;   // exclusive scan
}

__global__ void k_off(unsigned* __restrict__ hist, const unsigned* __restrict__ base) {
    int b = blockIdx.x * 256 + threadIdx.x;
    if (b >= NBK) return;
    unsigned run = base[b];
    for (int i = 0; i < NB; ++i) {
        size_t idx = (size_t)i * NBK + b;
        unsigned v = hist[idx];
        hist[idx] = run;    // hist becomes per-(block,bucket) scatter cursor base
        run += v;
    }
}

// Partition: LDS-staged, XOR-swizzled bins, coalesced 16-word flushes.
__global__ void __launch_bounds__(512, 4)
k_part(const int* __restrict__ src, const int* __restrict__ dst,
       const unsigned* __restrict__ off, unsigned* __restrict__ part) {
    __shared__ unsigned stage[NBK][CAP];   // 64 KB, swizzled: slot = pos ^ (b&15)
    __shared__ unsigned cnt[NBK];
    __shared__ unsigned goff[NBK];
    const unsigned* o = off + (size_t)blockIdx.x * NBK;
    for (int j = threadIdx.x; j < NBK; j += 512) { goff[j] = o[j]; cnt[j] = 0; }
    __syncthreads();
    int beg = blockIdx.x * CHUNK;
    int end = min(beg + CHUNK, N_EDGES);
    const int g  = threadIdx.x >> 4;   // 32 flush groups of 16 lanes
    const int gl = threadIdx.x & 15;
    for (int tb = beg; tb < end; tb += TILE) {
        int te = min(tb + TILE, end);
        // phase 1: stage into LDS bins (vectorized half-steps)
        for (int half = tb; half < te; half += 2048) {
            int he = min(half + 2048, te);
            int e = half + (int)threadIdx.x * 4;
            int s0, s1, s2, s3, d0, d1, d2, d3, cnt4 = 0;
            if (e + 4 <= he) {
                int4 d4 = *(const int4*)(dst + e);
                int4 s4 = *(const int4*)(src + e);
                d0 = d4.x; d1 = d4.y; d2 = d4.z; d3 = d4.w;
                s0 = s4.x; s1 = s4.y; s2 = s4.z; s3 = s4.w;
                cnt4 = 4;
            } else {
                int m = he - e;
                cnt4 = m < 0 ? 0 : m;
                if (cnt4 > 0) { d0 = dst[e];     s0 = src[e]; }
                if (cnt4 > 1) { d1 = dst[e + 1]; s1 = src[e + 1]; }
                if (cnt4 > 2) { d2 = dst[e + 2]; s2 = src[e + 2]; }
                if (cnt4 > 3) { d3 = dst[e + 3]; s3 = src[e + 3]; }
            }
            #pragma unroll
            for (int j = 0; j < 4; ++j) {
                if (j >= cnt4) break;
                int dd = j == 0 ? d0 : j == 1 ? d1 : j == 2 ? d2 : d3;
                int ss = j == 0 ? s0 : j == 1 ? s1 : j == 2 ? s2 : s3;
                unsigned b = ((unsigned)dd) >> 8;
                unsigned v = pack_edge((unsigned)ss, (unsigned)dd);
                unsigned pos = atomicAdd(&cnt[b], 1u);
                if (pos < CAP) stage[b][pos ^ (b & 15u)] = v;
                else part[atomicAdd(&goff[b], 1u)] = v;   // rare overflow (P ~ 4e-6)
            }
        }
        __syncthreads();
        const bool last = (te == end);
        // phase 2: coalesced flush of full 16-groups (residual carried across tiles)
        for (int b = g; b < NBK; b += 32) {
            const unsigned c = (unsigned)b & 15u;
            unsigned n = min(cnt[b], (unsigned)CAP);
            unsigned nfull = n >> 4, rem = n & 15u;    // nfull in {0,1} at CAP=16
            unsigned gbase = goff[b];
            for (unsigned k = 0; k < nfull; ++k)
                part[gbase + k * 16u + gl] = stage[b][(k * 16u + gl) ^ c];
            if (last) {
                if (gl < rem) part[gbase + nfull * 16u + gl] = stage[b][(nfull * 16u + gl) ^ c];
            }
            // non-last residual (only when nfull==0): stays in place, nothing to move
            if (gl == 0) {
                goff[b] = gbase + (last ? n : nfull * 16u);
                cnt[b]  = last ? 0u : rem;
            }
        }
        __syncthreads();
    }
}

// per-edge consumer loop: aligned uint4 body + scalar head/tail (256 threads)
#define BUCKET_EDGE_LOOP(EDGE_OP)                                              \
    unsigned st = base[blockIdx.x], tot = total[blockIdx.x];                   \
    unsigned en = st + tot;                                                    \
    unsigned a0 = (st + 3u) & ~3u; if (a0 > en) a0 = en;                       \
    unsigned a1 = en & ~3u;        if (a1 < a0) a1 = a0;                       \
    if (st + threadIdx.x < a0) { unsigned p = part[st + threadIdx.x]; EDGE_OP(p); } \
    for (unsigned k = a0 + threadIdx.x * 4u; k < a1; k += 1024u) {             \
        uint4 q = *(const uint4*)(part + k);                                   \
        EDGE_OP(q.x); EDGE_OP(q.y); EDGE_OP(q.z); EDGE_OP(q.w);                \
    }                                                                          \
    if (a1 + threadIdx.x < en) { unsigned p = part[a1 + threadIdx.x]; EDGE_OP(p); }

// deg per node (LDS counts) fused with dinv = rsqrt(deg), xs = x*dinv
__global__ void k_deg_dinv(const unsigned* __restrict__ part,
                           const unsigned* __restrict__ base, const unsigned* __restrict__ total,
                           const float* __restrict__ x,
                           float* __restrict__ dinv, float* __restrict__ xs) {
    __shared__ unsigned cnt[256];
    cnt[threadIdx.x] = 0;
    __syncthreads();
    #define DEG_OP(p) atomicAdd(&cnt[((p) >> 20) & 255u], 1u)
    BUCKET_EDGE_LOOP(DEG_OP)
    #undef DEG_OP
    __syncthreads();
    int n = blockIdx.x * 256 + threadIdx.x;
    if (n < N_NODES) {
        float di = rsqrtf((float)cnt[threadIdx.x] + 1.0f);  // +1 self-loop
        dinv[n] = di;
        xs[n] = x[n] * di;
    }
}

// layer-1 aggregation + fused 16-wide MLP epilogue:
// s = dinv*(acc + xs_self); t = sum relu(s*W1+b1)*W2; u = t*dinv; out = b2 + t*dinv^2
__global__ void k_agg1(const unsigned* __restrict__ part,
                       const unsigned* __restrict__ base, const unsigned* __restrict__ total,
                       const float* __restrict__ xs, const float* __restrict__ dinv,
                       const float* __restrict__ W1, const float* __restrict__ b1,
                       const float* __restrict__ W2, const float* __restrict__ b2,
                       float* __restrict__ u, float* __restrict__ out) {
    __shared__ float acc[256];
    acc[threadIdx.x] = 0.f;
    __syncthreads();
    #define AGG1_OP(p) atomicAdd(&acc[((p) >> 20) & 255u], xs[(p) & 0x3FFFFu])
    BUCKET_EDGE_LOOP(AGG1_OP)
    #undef AGG1_OP
    __syncthreads();
    int n = blockIdx.x * 256 + threadIdx.x;
    if (n < N_NODES) {
        float di = dinv[n];
        float sv = di * (acc[threadIdx.x] + xs[n]);
        float t = 0.f;
        #pragma unroll
        for (int k = 0; k < 16; ++k)
            t = fmaf(fmaxf(fmaf(sv, W1[k], b1[k]), 0.f), W2[k], t);
        u[n] = t * di;
        out[n] = b2[0] + t * di * di;   // layer-2 self-loop + bias
    }
}

// layer-2 aggregation: out += dinv * sum(u[src])
__global__ void k_agg2(const unsigned* __restrict__ part,
                       const unsigned* __restrict__ base, const unsigned* __restrict__ total,
                       const float* __restrict__ u, const float* __restrict__ dinv,
                       float* __restrict__ out) {
    __shared__ float acc[256];
    acc[threadIdx.x] = 0.f;
    __syncthreads();
    #define AGG2_OP(p) atomicAdd(&acc[((p) >> 20) & 255u], u[(p) & 0x3FFFFu])
    BUCKET_EDGE_LOOP(AGG2_OP)
    #undef AGG2_OP
    __syncthreads();
    int n = blockIdx.x * 256 + threadIdx.x;
    if (n < N_NODES) out[n] += dinv[n] * acc[threadIdx.x];
}

// ---- fallback path (device atomics) if ws is too small ----
__global__ void f_init(float* __restrict__ deg) {
    int n = blockIdx.x * blockDim.x + threadIdx.x;
    if (n < N_NODES) deg[n] = 1.0f;
}
__global__ void f_deg(const int* __restrict__ dst, float* __restrict__ deg) {
    int e = blockIdx.x * blockDim.x + threadIdx.x;
    if (e < N_EDGES) atomicAdd(&deg[dst[e]], 1.0f);
}
__global__ void f_node1(const float* __restrict__ x, const float* __restrict__ deg,
                        float* __restrict__ dinv, float* __restrict__ xs,
                        float* __restrict__ s) {
    int n = blockIdx.x * blockDim.x + threadIdx.x;
    if (n < N_NODES) {
        float di = rsqrtf(deg[n]);
        float xv = x[n];
        dinv[n] = di; xs[n] = xv * di; s[n] = xv * di * di;
    }
}
__global__ void f_sc1(const int* __restrict__ src, const int* __restrict__ dst,
                      const float* __restrict__ xs, const float* __restrict__ dinv,
                      float* __restrict__ s) {
    int e = blockIdx.x * blockDim.x + threadIdx.x;
    if (e < N_EDGES) atomicAdd(&s[dst[e]], xs[src[e]] * dinv[dst[e]]);
}
__global__ void f_node2(const float* __restrict__ s, const float* __restrict__ dinv,
                        const float* __restrict__ W1, const float* __restrict__ b1,
                        const float* __restrict__ W2, const float* __restrict__ b2,
                        float* __restrict__ u, float* __restrict__ out) {
    int n = blockIdx.x * blockDim.x + threadIdx.x;
    if (n < N_NODES) {
        float sv = s[n], acc = 0.0f;
        #pragma unroll
        for (int k = 0; k < 16; ++k)
            acc = fmaf(fmaxf(fmaf(sv, W1[k], b1[k]), 0.f), W2[k], acc);
        float di = dinv[n];
        u[n] = acc * di; out[n] = b2[0] + acc * di * di;
    }
}
__global__ void f_sc2(const int* __restrict__ src, const int* __restrict__ dst,
                      const float* __restrict__ u, const float* __restrict__ dinv,
                      float* __restrict__ out) {
    int e = blockIdx.x * blockDim.x + threadIdx.x;
    if (e < N_EDGES) atomicAdd(&out[dst[e]], u[src[e]] * dinv[dst[e]]);
}

extern "C" void kernel_launch(void* const* d_in, const int* in_sizes, int n_in,
                              void* d_out, int out_size, void* d_ws, size_t ws_size,
                              hipStream_t stream) {
    const float* x  = (const float*)d_in[0];
    const int*   ei = (const int*)d_in[1];
    const float* W1 = (const float*)d_in[2];
    const float* b1 = (const float*)d_in[3];
    const float* W2 = (const float*)d_in[4];
    const float* b2 = (const float*)d_in[5];
    float* out = (float*)d_out;
    const int* src = ei;
    const int* dst = ei + N_EDGES;

    // Layout: hist (2MB, later aliased by u+dinv), total, base, part (20MB), xs.
    // u+dinv (2MB) fit inside the dead hist region after k_part.
    const size_t need = ((size_t)NB * NBK + 2 * NBK + N_EDGES + N_NODES) * 4;

    if (ws_size >= need) {
        unsigned* hist  = (unsigned*)d_ws;
        unsigned* total = hist + (size_t)NB * NBK;
        unsigned* base  = total + NBK;
        unsigned* part  = base + NBK;
        float* xs   = (float*)(part + N_EDGES);
        float* dinv = (float*)hist;            // aliases dead hist (after k_part)
        float* u    = dinv + N_NODES;          // still inside the 2MB hist region

        k_hist    <<<NB, 512, 0, stream>>>(dst, hist);
        k_total   <<<NBK / 256, 256, 0, stream>>>(hist, total);
        k_scanbase<<<1, NBK, 0, stream>>>(total, base);
        k_off     <<<NBK / 256, 256, 0, stream>>>(hist, base);
        k_part    <<<NB, 512, 0, stream>>>(src, dst, hist, part);
        k_deg_dinv<<<NBUCK, 256, 0, stream>>>(part, base, total, x, dinv, xs);
        k_agg1    <<<NBUCK, 256, 0, stream>>>(part, base, total, xs, dinv, W1, b1, W2, b2, u, out);
        k_agg2    <<<NBUCK, 256, 0, stream>>>(part, base, total, u, dinv, out);
    } else {
        float* deg  = (float*)d_ws;
        float* dinv = deg + N_NODES;
        float* xs   = dinv + N_NODES;
        float* s    = xs + N_NODES;
        float* u    = deg;
        const int TB = 256;
        const int gn = (N_NODES + TB - 1) / TB;
        const int ge = (N_EDGES + TB - 1) / TB;
        f_init <<<gn, TB, 0, stream>>>(deg);
        f_deg  <<<ge, TB, 0, stream>>>(dst, deg);
        f_node1<<<gn, TB, 0, stream>>>(x, deg, dinv, xs, s);
        f_sc1  <<<ge, TB, 0, stream>>>(src, dst, xs, dinv, s);
        f_node2<<<gn, TB, 0, stream>>>(s, dinv, W1, b1, W2, b2, u, out);
        f_sc2  <<<ge, TB, 0, stream>>>(src, dst, u, dinv, out);
    }
}

// Round 8
// 99.981 us; speedup vs baseline: 2.3458x; 1.3273x over previous
//
#include <hip/hip_runtime.h>

static constexpr int N_NODES = 250000;
static constexpr int N_EDGES = 5000000;

// ---- single-pass counting-sort by dst>>9 into 512-node buckets ----
static constexpr int NB    = 512;                       // partition blocks
static constexpr int CHUNK = 9768;                      // per-block edges; NB*CHUNK >= N_EDGES
static constexpr int NBK   = 512;                       // buckets (dst>>9); 489 used
static constexpr int NBUCK = (N_NODES + 511) / 512;     // 489 consumer blocks
static constexpr int BCAP  = 12288;                     // per-bucket region (mean 10225, +20 sigma)

// pack: bits 0..17 = src (N < 2^18), bits 20..28 = dst & 511
__device__ __forceinline__ unsigned pack_edge(unsigned s, unsigned d) {
    return s | ((d & 511u) << 20);
}

__global__ void z_init(unsigned* __restrict__ glen) {
    // glen[0..511] bucket cursors, glen[512] spill cursor, + pad to 520.
    // 1024 threads so every word (incl. glen[512]) is covered — round-7 bug
    // was a 512-thread launch leaving glen[512] poisoned (0xAA..) -> OOB reads.
    int j = threadIdx.x;
    if (j < 520) glen[j] = 0;
}

// Single-pass partition: LDS histogram -> scan -> device reservation ->
// LDS bucket-scatter -> coalesced per-bucket run copy-out.
__global__ void __launch_bounds__(512, 6)
k_part_sp(const int* __restrict__ src, const int* __restrict__ dst,
          unsigned* __restrict__ glen, unsigned* __restrict__ part,
          uint2* __restrict__ spill) {
    __shared__ unsigned h[NBK];       // bucket counts (preserved)
    __shared__ unsigned loffE[NBK];   // exclusive scan
    __shared__ unsigned cur[NBK];     // scatter cursors
    __shared__ unsigned gb[NBK];      // reserved global offset within bucket region
    __shared__ unsigned ebuf[CHUNK];  // 38.2 KB bucket-ordered edges
    const int t = threadIdx.x;
    const int beg = blockIdx.x * CHUNK;
    const int end = min(beg + CHUNK, N_EDGES);

    h[t] = 0;
    __syncthreads();

    // ---- phase A: histogram dst buckets ----
    for (int e = beg + t * 4; e < end; e += 2048) {
        if (e + 4 <= end) {
            int4 d4 = *(const int4*)(dst + e);
            atomicAdd(&h[((unsigned)d4.x) >> 9], 1u);
            atomicAdd(&h[((unsigned)d4.y) >> 9], 1u);
            atomicAdd(&h[((unsigned)d4.z) >> 9], 1u);
            atomicAdd(&h[((unsigned)d4.w) >> 9], 1u);
        } else {
            for (int j = 0; j < 4 && e + j < end; ++j)
                atomicAdd(&h[((unsigned)dst[e + j]) >> 9], 1u);
        }
    }
    __syncthreads();

    // ---- phase B: block scan + one device reservation per bucket ----
    unsigned v = h[t];
    loffE[t] = v;
    __syncthreads();
    for (int off = 1; off < NBK; off <<= 1) {
        unsigned a = (t >= off) ? loffE[t - off] : 0u;
        __syncthreads();
        loffE[t] += a;
        __syncthreads();
    }
    loffE[t] -= v;              // exclusive
    cur[t] = loffE[t];
    gb[t] = v ? atomicAdd(&glen[t], v) : 0u;   // reserve once per (block,bucket)
    __syncthreads();

    // ---- phase C: re-read edges (L2-warm), scatter into LDS by bucket ----
    for (int e = beg + t * 4; e < end; e += 2048) {
        if (e + 4 <= end) {
            int4 d4 = *(const int4*)(dst + e);
            int4 s4 = *(const int4*)(src + e);
            #pragma unroll
            for (int j = 0; j < 4; ++j) {
                int dd = j == 0 ? d4.x : j == 1 ? d4.y : j == 2 ? d4.z : d4.w;
                int ss = j == 0 ? s4.x : j == 1 ? s4.y : j == 2 ? s4.z : s4.w;
                unsigned b = ((unsigned)dd) >> 9;
                ebuf[atomicAdd(&cur[b], 1u)] = pack_edge((unsigned)ss, (unsigned)dd);
            }
        } else {
            for (int j = 0; j < 4 && e + j < end; ++j) {
                unsigned dd = (unsigned)dst[e + j], ss = (unsigned)src[e + j];
                ebuf[atomicAdd(&cur[dd >> 9], 1u)] = pack_edge(ss, dd);
            }
        }
    }
    __syncthreads();

    // ---- phase D: coalesced per-bucket run copy-out (+ spill, never in practice) ----
    const int g  = t >> 4;     // 32 groups of 16 lanes (groups never straddle a wave)
    const int gl = t & 15;
    for (int b = g; b < NBK; b += 32) {
        unsigned n = h[b];
        if (!n) continue;
        unsigned lo = loffE[b], base = gb[b];
        unsigned room = (base < (unsigned)BCAP) ? min(n, (unsigned)BCAP - base) : 0u;
        unsigned* dstp = part + (size_t)b * BCAP + base;
        for (unsigned i = gl; i < room; i += 16) dstp[i] = ebuf[lo + i];
        unsigned nsp = n - room;
        if (nsp) {   // overflow -> spill (uint2: src, full dst)
            unsigned spos = 0;
            if (gl == 0) spos = atomicAdd(&glen[NBK], nsp);
            spos = __shfl(spos, (int)((t & 63) & ~15), 64);
            for (unsigned i = gl; i < nsp; i += 16) {
                unsigned pe = ebuf[lo + room + i];
                spill[spos + i] = make_uint2(pe & 0x3FFFFu, ((unsigned)b << 9) | (pe >> 20));
            }
        }
    }
}

// consumer edge loop over bucket region [b*BCAP, b*BCAP+tot), 512 threads
#define BUCKET_EDGE_LOOP(EDGE_OP)                                              \
    const unsigned st = (unsigned)blockIdx.x * (unsigned)BCAP;                 \
    const unsigned tot = min(glen[blockIdx.x], (unsigned)BCAP);                \
    const unsigned a1 = st + (tot & ~3u);                                      \
    for (unsigned k = st + threadIdx.x * 4u; k < a1; k += 2048u) {             \
        uint4 q = *(const uint4*)(part + k);                                   \
        EDGE_OP(q.x); EDGE_OP(q.y); EDGE_OP(q.z); EDGE_OP(q.w);                \
    }                                                                          \
    if (a1 + threadIdx.x < st + tot) { unsigned p = part[a1 + threadIdx.x]; EDGE_OP(p); }

// deg per node (LDS counts) fused with dinv = rsqrt(deg), xs = x*dinv
__global__ void k_deg_dinv(const unsigned* __restrict__ part, const unsigned* __restrict__ glen,
                           const uint2* __restrict__ spill,
                           const float* __restrict__ x,
                           float* __restrict__ dinv, float* __restrict__ xs) {
    __shared__ unsigned cnt[512];
    cnt[threadIdx.x] = 0;
    __syncthreads();
    #define DEG_OP(p) atomicAdd(&cnt[((p) >> 20) & 511u], 1u)
    BUCKET_EDGE_LOOP(DEG_OP)
    #undef DEG_OP
    unsigned sl = glen[NBK];
    for (unsigned k = threadIdx.x; k < sl; k += 512u) {
        uint2 e = spill[k];
        if ((e.y >> 9) == (unsigned)blockIdx.x) atomicAdd(&cnt[e.y & 511u], 1u);
    }
    __syncthreads();
    int n = blockIdx.x * 512 + threadIdx.x;
    if (n < N_NODES) {
        float di = rsqrtf((float)cnt[threadIdx.x] + 1.0f);  // +1 self-loop
        dinv[n] = di;
        xs[n] = x[n] * di;
    }
}

// layer-1 aggregation + fused 16-wide MLP epilogue
__global__ void k_agg1(const unsigned* __restrict__ part, const unsigned* __restrict__ glen,
                       const uint2* __restrict__ spill,
                       const float* __restrict__ xs, const float* __restrict__ dinv,
                       const float* __restrict__ W1, const float* __restrict__ b1,
                       const float* __restrict__ W2, const float* __restrict__ b2,
                       float* __restrict__ u, float* __restrict__ out) {
    __shared__ float acc[512];
    acc[threadIdx.x] = 0.f;
    __syncthreads();
    #define AGG1_OP(p) atomicAdd(&acc[((p) >> 20) & 511u], xs[(p) & 0x3FFFFu])
    BUCKET_EDGE_LOOP(AGG1_OP)
    #undef AGG1_OP
    unsigned sl = glen[NBK];
    for (unsigned k = threadIdx.x; k < sl; k += 512u) {
        uint2 e = spill[k];
        if ((e.y >> 9) == (unsigned)blockIdx.x) atomicAdd(&acc[e.y & 511u], xs[e.x]);
    }
    __syncthreads();
    int n = blockIdx.x * 512 + threadIdx.x;
    if (n < N_NODES) {
        float di = dinv[n];
        float sv = di * (acc[threadIdx.x] + xs[n]);
        float t = 0.f;
        #pragma unroll
        for (int k = 0; k < 16; ++k)
            t = fmaf(fmaxf(fmaf(sv, W1[k], b1[k]), 0.f), W2[k], t);
        u[n] = t * di;
        out[n] = b2[0] + t * di * di;   // layer-2 self-loop + bias
    }
}

// layer-2 aggregation: out += dinv * sum(u[src])
__global__ void k_agg2(const unsigned* __restrict__ part, const unsigned* __restrict__ glen,
                       const uint2* __restrict__ spill,
                       const float* __restrict__ u, const float* __restrict__ dinv,
                       float* __restrict__ out) {
    __shared__ float acc[512];
    acc[threadIdx.x] = 0.f;
    __syncthreads();
    #define AGG2_OP(p) atomicAdd(&acc[((p) >> 20) & 511u], u[(p) & 0x3FFFFu])
    BUCKET_EDGE_LOOP(AGG2_OP)
    #undef AGG2_OP
    unsigned sl = glen[NBK];
    for (unsigned k = threadIdx.x; k < sl; k += 512u) {
        uint2 e = spill[k];
        if ((e.y >> 9) == (unsigned)blockIdx.x) atomicAdd(&acc[e.y & 511u], u[e.x]);
    }
    __syncthreads();
    int n = blockIdx.x * 512 + threadIdx.x;
    if (n < N_NODES) out[n] += dinv[n] * acc[threadIdx.x];
}

// ---- fallback path (device atomics) if ws is too small ----
__global__ void f_init(float* __restrict__ deg) {
    int n = blockIdx.x * blockDim.x + threadIdx.x;
    if (n < N_NODES) deg[n] = 1.0f;
}
__global__ void f_deg(const int* __restrict__ dst, float* __restrict__ deg) {
    int e = blockIdx.x * blockDim.x + threadIdx.x;
    if (e < N_EDGES) atomicAdd(&deg[dst[e]], 1.0f);
}
__global__ void f_node1(const float* __restrict__ x, const float* __restrict__ deg,
                        float* __restrict__ dinv, float* __restrict__ xs,
                        float* __restrict__ s) {
    int n = blockIdx.x * blockDim.x + threadIdx.x;
    if (n < N_NODES) {
        float di = rsqrtf(deg[n]);
        float xv = x[n];
        dinv[n] = di; xs[n] = xv * di; s[n] = xv * di * di;
    }
}
__global__ void f_sc1(const int* __restrict__ src, const int* __restrict__ dst,
                      const float* __restrict__ xs, const float* __restrict__ dinv,
                      float* __restrict__ s) {
    int e = blockIdx.x * blockDim.x + threadIdx.x;
    if (e < N_EDGES) atomicAdd(&s[dst[e]], xs[src[e]] * dinv[dst[e]]);
}
__global__ void f_node2(const float* __restrict__ s, const float* __restrict__ dinv,
                        const float* __restrict__ W1, const float* __restrict__ b1,
                        const float* __restrict__ W2, const float* __restrict__ b2,
                        float* __restrict__ u, float* __restrict__ out) {
    int n = blockIdx.x * blockDim.x + threadIdx.x;
    if (n < N_NODES) {
        float sv = s[n], acc = 0.0f;
        #pragma unroll
        for (int k = 0; k < 16; ++k)
            acc = fmaf(fmaxf(fmaf(sv, W1[k], b1[k]), 0.f), W2[k], acc);
        float di = dinv[n];
        u[n] = acc * di; out[n] = b2[0] + acc * di * di;
    }
}
__global__ void f_sc2(const int* __restrict__ src, const int* __restrict__ dst,
                      const float* __restrict__ u, const float* __restrict__ dinv,
                      float* __restrict__ out) {
    int e = blockIdx.x * blockDim.x + threadIdx.x;
    if (e < N_EDGES) atomicAdd(&out[dst[e]], u[src[e]] * dinv[dst[e]]);
}

extern "C" void kernel_launch(void* const* d_in, const int* in_sizes, int n_in,
                              void* d_out, int out_size, void* d_ws, size_t ws_size,
                              hipStream_t stream) {
    const float* x  = (const float*)d_in[0];
    const int*   ei = (const int*)d_in[1];
    const float* W1 = (const float*)d_in[2];
    const float* b1 = (const float*)d_in[3];
    const float* W2 = (const float*)d_in[4];
    const float* b2 = (const float*)d_in[5];
    float* out = (float*)d_out;
    const int* src = ei;
    const int* dst = ei + N_EDGES;

    // ws layout (u32 units): part[NBK*BCAP] | spill[N_EDGES uint2] | glen[520] | xs | dinv | u
    const size_t partN  = (size_t)NBK * BCAP;              // 6,291,456
    const size_t spillN = (size_t)N_EDGES * 2;             // uint2
    const size_t need   = (partN + spillN + 520 + 3 * (size_t)N_NODES) * 4;

    if (ws_size >= need) {
        unsigned* part  = (unsigned*)d_ws;
        uint2*    spill = (uint2*)(part + partN);
        unsigned* glen  = (unsigned*)(part + partN + spillN);
        float*    xs    = (float*)(glen + 520);
        float*    dinv  = xs + N_NODES;
        float*    u     = dinv + N_NODES;

        z_init    <<<1, 1024, 0, stream>>>(glen);
        k_part_sp <<<NB, 512, 0, stream>>>(src, dst, glen, part, spill);
        k_deg_dinv<<<NBUCK, 512, 0, stream>>>(part, glen, spill, x, dinv, xs);
        k_agg1    <<<NBUCK, 512, 0, stream>>>(part, glen, spill, xs, dinv, W1, b1, W2, b2, u, out);
        k_agg2    <<<NBUCK, 512, 0, stream>>>(part, glen, spill, u, dinv, out);
    } else {
        float* deg  = (float*)d_ws;
        float* dinv = deg + N_NODES;
        float* xs   = dinv + N_NODES;
        float* s    = xs + N_NODES;
        float* u    = deg;
        const int TB = 256;
        const int gn = (N_NODES + TB - 1) / TB;
        const int ge = (N_EDGES + TB - 1) / TB;
        f_init <<<gn, TB, 0, stream>>>(deg);
        f_deg  <<<ge, TB, 0, stream>>>(dst, deg);
        f_node1<<<gn, TB, 0, stream>>>(x, deg, dinv, xs, s);
        f_sc1  <<<ge, TB, 0, stream>>>(src, dst, xs, dinv, s);
        f_node2<<<gn, TB, 0, stream>>>(s, dinv, W1, b1, W2, b2, u, out);
        f_sc2  <<<ge, TB, 0, stream>>>(src, dst, u, dinv, out);
    }
}

// Round 9
// 98.609 us; speedup vs baseline: 2.3784x; 1.0139x over previous
//
#include <hip/hip_runtime.h>

static constexpr int N_NODES = 250000;
static constexpr int N_EDGES = 5000000;

// ---- single-pass counting-sort by dst>>9 into 512-node buckets ----
static constexpr int NB    = 512;                       // partition blocks
static constexpr int CHUNK = 9768;                      // per-block edges; NB*CHUNK >= N_EDGES
static constexpr int NBK   = 512;                       // buckets (dst>>9); 489 used
static constexpr int NBUCK = (N_NODES + 511) / 512;     // 489 consumer blocks
static constexpr int BCAP  = 12288;                     // per-bucket region (mean 10225, +20 sigma)

// pack: bits 0..17 = src (N < 2^18), bits 20..28 = dst & 511
__device__ __forceinline__ unsigned pack_edge(unsigned s, unsigned d) {
    return s | ((d & 511u) << 20);
}

__global__ void z_init(unsigned* __restrict__ glen) {
    // glen[0..511] bucket cursors, glen[512] spill cursor, + pad to 520.
    int j = threadIdx.x;
    if (j < 520) glen[j] = 0;
}

// Single-pass partition: LDS histogram -> scan -> device reservation ->
// LDS bucket-scatter -> coalesced per-bucket run copy-out.  1024 threads.
__global__ void __launch_bounds__(1024, 8)
k_part_sp(const int* __restrict__ src, const int* __restrict__ dst,
          unsigned* __restrict__ glen, unsigned* __restrict__ part,
          uint2* __restrict__ spill) {
    __shared__ unsigned h[NBK];       // bucket counts (preserved)
    __shared__ unsigned loffE[NBK];   // exclusive scan
    __shared__ unsigned cur[NBK];     // scatter cursors
    __shared__ unsigned gb[NBK];      // reserved global offset within bucket region
    __shared__ unsigned ebuf[CHUNK];  // 38.2 KB bucket-ordered edges
    const int t = threadIdx.x;
    const int beg = blockIdx.x * CHUNK;
    const int end = min(beg + CHUNK, N_EDGES);

    if (t < NBK) h[t] = 0;
    __syncthreads();

    // ---- phase A: histogram dst buckets ----
    for (int e = beg + t * 4; e < end; e += 4096) {
        if (e + 4 <= end) {
            int4 d4 = *(const int4*)(dst + e);
            atomicAdd(&h[((unsigned)d4.x) >> 9], 1u);
            atomicAdd(&h[((unsigned)d4.y) >> 9], 1u);
            atomicAdd(&h[((unsigned)d4.z) >> 9], 1u);
            atomicAdd(&h[((unsigned)d4.w) >> 9], 1u);
        } else {
            for (int j = 0; j < 4 && e + j < end; ++j)
                atomicAdd(&h[((unsigned)dst[e + j]) >> 9], 1u);
        }
    }
    __syncthreads();

    // ---- phase B: block scan (threads < NBK) + one device reservation per bucket ----
    unsigned v = 0;
    if (t < NBK) { v = h[t]; loffE[t] = v; }
    __syncthreads();
    for (int off = 1; off < NBK; off <<= 1) {
        unsigned a = 0;
        if (t < NBK && t >= off) a = loffE[t - off];
        __syncthreads();
        if (t < NBK) loffE[t] += a;
        __syncthreads();
    }
    if (t < NBK) {
        loffE[t] -= v;              // exclusive
        cur[t] = loffE[t];
        gb[t] = v ? atomicAdd(&glen[t], v) : 0u;   // reserve once per (block,bucket)
    }
    __syncthreads();

    // ---- phase C: re-read edges (L2-warm), scatter into LDS by bucket ----
    for (int e = beg + t * 4; e < end; e += 4096) {
        if (e + 4 <= end) {
            int4 d4 = *(const int4*)(dst + e);
            int4 s4 = *(const int4*)(src + e);
            #pragma unroll
            for (int j = 0; j < 4; ++j) {
                int dd = j == 0 ? d4.x : j == 1 ? d4.y : j == 2 ? d4.z : d4.w;
                int ss = j == 0 ? s4.x : j == 1 ? s4.y : j == 2 ? s4.z : s4.w;
                unsigned b = ((unsigned)dd) >> 9;
                ebuf[atomicAdd(&cur[b], 1u)] = pack_edge((unsigned)ss, (unsigned)dd);
            }
        } else {
            for (int j = 0; j < 4 && e + j < end; ++j) {
                unsigned dd = (unsigned)dst[e + j], ss = (unsigned)src[e + j];
                ebuf[atomicAdd(&cur[dd >> 9], 1u)] = pack_edge(ss, dd);
            }
        }
    }
    __syncthreads();

    // ---- phase D: coalesced per-bucket run copy-out (+ spill, never in practice) ----
    const int g  = t >> 4;     // 64 groups of 16 lanes (groups never straddle a wave)
    const int gl = t & 15;
    for (int b = g; b < NBK; b += 64) {
        unsigned n = h[b];
        if (!n) continue;
        unsigned lo = loffE[b], base = gb[b];
        unsigned room = (base < (unsigned)BCAP) ? min(n, (unsigned)BCAP - base) : 0u;
        unsigned* dstp = part + (size_t)b * BCAP + base;
        for (unsigned i = gl; i < room; i += 16) dstp[i] = ebuf[lo + i];
        unsigned nsp = n - room;
        if (nsp) {   // overflow -> spill (uint2: src, full dst)
            unsigned spos = 0;
            if (gl == 0) spos = atomicAdd(&glen[NBK], nsp);
            spos = __shfl(spos, (int)((t & 63) & ~15), 64);
            for (unsigned i = gl; i < nsp; i += 16) {
                unsigned pe = ebuf[lo + room + i];
                spill[spos + i] = make_uint2(pe & 0x3FFFFu, ((unsigned)b << 9) | (pe >> 20));
            }
        }
    }
}

// consumer edge loop over bucket region [b*BCAP, b*BCAP+tot), 1024 threads
#define BUCKET_EDGE_LOOP(EDGE_OP)                                              \
    const unsigned st = (unsigned)blockIdx.x * (unsigned)BCAP;                 \
    const unsigned tot = min(glen[blockIdx.x], (unsigned)BCAP);                \
    const unsigned a1 = st + (tot & ~3u);                                      \
    for (unsigned k = st + threadIdx.x * 4u; k < a1; k += 4096u) {             \
        uint4 q = *(const uint4*)(part + k);                                   \
        EDGE_OP(q.x); EDGE_OP(q.y); EDGE_OP(q.z); EDGE_OP(q.w);                \
    }                                                                          \
    if (a1 + threadIdx.x < st + tot) { unsigned p = part[a1 + threadIdx.x]; EDGE_OP(p); }

// deg per node (LDS counts) fused with dinv = rsqrt(deg), xs = x*dinv
__global__ void __launch_bounds__(1024, 8)
k_deg_dinv(const unsigned* __restrict__ part, const unsigned* __restrict__ glen,
           const uint2* __restrict__ spill,
           const float* __restrict__ x,
           float* __restrict__ dinv, float* __restrict__ xs) {
    __shared__ unsigned cnt[512];
    if (threadIdx.x < 512) cnt[threadIdx.x] = 0;
    __syncthreads();
    #define DEG_OP(p) atomicAdd(&cnt[((p) >> 20) & 511u], 1u)
    BUCKET_EDGE_LOOP(DEG_OP)
    #undef DEG_OP
    unsigned sl = glen[NBK];
    for (unsigned k = threadIdx.x; k < sl; k += 1024u) {
        uint2 e = spill[k];
        if ((e.y >> 9) == (unsigned)blockIdx.x) atomicAdd(&cnt[e.y & 511u], 1u);
    }
    __syncthreads();
    if (threadIdx.x < 512) {
        int n = blockIdx.x * 512 + (int)threadIdx.x;
        if (n < N_NODES) {
            float di = rsqrtf((float)cnt[threadIdx.x] + 1.0f);  // +1 self-loop
            dinv[n] = di;
            xs[n] = x[n] * di;
        }
    }
}

// layer-1 aggregation + fused 16-wide MLP epilogue
__global__ void __launch_bounds__(1024, 8)
k_agg1(const unsigned* __restrict__ part, const unsigned* __restrict__ glen,
       const uint2* __restrict__ spill,
       const float* __restrict__ xs, const float* __restrict__ dinv,
       const float* __restrict__ W1, const float* __restrict__ b1,
       const float* __restrict__ W2, const float* __restrict__ b2,
       float* __restrict__ u, float* __restrict__ out) {
    __shared__ float acc[512];
    if (threadIdx.x < 512) acc[threadIdx.x] = 0.f;
    __syncthreads();
    #define AGG1_OP(p) atomicAdd(&acc[((p) >> 20) & 511u], xs[(p) & 0x3FFFFu])
    BUCKET_EDGE_LOOP(AGG1_OP)
    #undef AGG1_OP
    unsigned sl = glen[NBK];
    for (unsigned k = threadIdx.x; k < sl; k += 1024u) {
        uint2 e = spill[k];
        if ((e.y >> 9) == (unsigned)blockIdx.x) atomicAdd(&acc[e.y & 511u], xs[e.x]);
    }
    __syncthreads();
    if (threadIdx.x < 512) {
        int n = blockIdx.x * 512 + (int)threadIdx.x;
        if (n < N_NODES) {
            float di = dinv[n];
            float sv = di * (acc[threadIdx.x] + xs[n]);
            float t = 0.f;
            #pragma unroll
            for (int k = 0; k < 16; ++k)
                t = fmaf(fmaxf(fmaf(sv, W1[k], b1[k]), 0.f), W2[k], t);
            u[n] = t * di;
            out[n] = b2[0] + t * di * di;   // layer-2 self-loop + bias
        }
    }
}

// layer-2 aggregation: out += dinv * sum(u[src])
__global__ void __launch_bounds__(1024, 8)
k_agg2(const unsigned* __restrict__ part, const unsigned* __restrict__ glen,
       const uint2* __restrict__ spill,
       const float* __restrict__ u, const float* __restrict__ dinv,
       float* __restrict__ out) {
    __shared__ float acc[512];
    if (threadIdx.x < 512) acc[threadIdx.x] = 0.f;
    __syncthreads();
    #define AGG2_OP(p) atomicAdd(&acc[((p) >> 20) & 511u], u[(p) & 0x3FFFFu])
    BUCKET_EDGE_LOOP(AGG2_OP)
    #undef AGG2_OP
    unsigned sl = glen[NBK];
    for (unsigned k = threadIdx.x; k < sl; k += 1024u) {
        uint2 e = spill[k];
        if ((e.y >> 9) == (unsigned)blockIdx.x) atomicAdd(&acc[e.y & 511u], u[e.x]);
    }
    __syncthreads();
    if (threadIdx.x < 512) {
        int n = blockIdx.x * 512 + (int)threadIdx.x;
        if (n < N_NODES) out[n] += dinv[n] * acc[threadIdx.x];
    }
}

// ---- fallback path (device atomics) if ws is too small ----
__global__ void f_init(float* __restrict__ deg) {
    int n = blockIdx.x * blockDim.x + threadIdx.x;
    if (n < N_NODES) deg[n] = 1.0f;
}
__global__ void f_deg(const int* __restrict__ dst, float* __restrict__ deg) {
    int e = blockIdx.x * blockDim.x + threadIdx.x;
    if (e < N_EDGES) atomicAdd(&deg[dst[e]], 1.0f);
}
__global__ void f_node1(const float* __restrict__ x, const float* __restrict__ deg,
                        float* __restrict__ dinv, float* __restrict__ xs,
                        float* __restrict__ s) {
    int n = blockIdx.x * blockDim.x + threadIdx.x;
    if (n < N_NODES) {
        float di = rsqrtf(deg[n]);
        float xv = x[n];
        dinv[n] = di; xs[n] = xv * di; s[n] = xv * di * di;
    }
}
__global__ void f_sc1(const int* __restrict__ src, const int* __restrict__ dst,
                      const float* __restrict__ xs, const float* __restrict__ dinv,
                      float* __restrict__ s) {
    int e = blockIdx.x * blockDim.x + threadIdx.x;
    if (e < N_EDGES) atomicAdd(&s[dst[e]], xs[src[e]] * dinv[dst[e]]);
}
__global__ void f_node2(const float* __restrict__ s, const float* __restrict__ dinv,
                        const float* __restrict__ W1, const float* __restrict__ b1,
                        const float* __restrict__ W2, const float* __restrict__ b2,
                        float* __restrict__ u, float* __restrict__ out) {
    int n = blockIdx.x * blockDim.x + threadIdx.x;
    if (n < N_NODES) {
        float sv = s[n], acc = 0.0f;
        #pragma unroll
        for (int k = 0; k < 16; ++k)
            acc = fmaf(fmaxf(fmaf(sv, W1[k], b1[k]), 0.f), W2[k], acc);
        float di = dinv[n];
        u[n] = acc * di; out[n] = b2[0] + acc * di * di;
    }
}
__global__ void f_sc2(const int* __restrict__ src, const int* __restrict__ dst,
                      const float* __restrict__ u, const float* __restrict__ dinv,
                      float* __restrict__ out) {
    int e = blockIdx.x * blockDim.x + threadIdx.x;
    if (e < N_EDGES) atomicAdd(&out[dst[e]], u[src[e]] * dinv[dst[e]]);
}

extern "C" void kernel_launch(void* const* d_in, const int* in_sizes, int n_in,
                              void* d_out, int out_size, void* d_ws, size_t ws_size,
                              hipStream_t stream) {
    const float* x  = (const float*)d_in[0];
    const int*   ei = (const int*)d_in[1];
    const float* W1 = (const float*)d_in[2];
    const float* b1 = (const float*)d_in[3];
    const float* W2 = (const float*)d_in[4];
    const float* b2 = (const float*)d_in[5];
    float* out = (float*)d_out;
    const int* src = ei;
    const int* dst = ei + N_EDGES;

    // ws layout (u32 units): part[NBK*BCAP] | spill[N_EDGES uint2] | glen[520] | xs | dinv | u
    const size_t partN  = (size_t)NBK * BCAP;              // 6,291,456
    const size_t spillN = (size_t)N_EDGES * 2;             // uint2
    const size_t need   = (partN + spillN + 520 + 3 * (size_t)N_NODES) * 4;

    if (ws_size >= need) {
        unsigned* part  = (unsigned*)d_ws;
        uint2*    spill = (uint2*)(part + partN);
        unsigned* glen  = (unsigned*)(part + partN + spillN);
        float*    xs    = (float*)(glen + 520);
        float*    dinv  = xs + N_NODES;
        float*    u     = dinv + N_NODES;

        z_init    <<<1, 1024, 0, stream>>>(glen);
        k_part_sp <<<NB, 1024, 0, stream>>>(src, dst, glen, part, spill);
        k_deg_dinv<<<NBUCK, 1024, 0, stream>>>(part, glen, spill, x, dinv, xs);
        k_agg1    <<<NBUCK, 1024, 0, stream>>>(part, glen, spill, xs, dinv, W1, b1, W2, b2, u, out);
        k_agg2    <<<NBUCK, 1024, 0, stream>>>(part, glen, spill, u, dinv, out);
    } else {
        float* deg  = (float*)d_ws;
        float* dinv = deg + N_NODES;
        float* xs   = dinv + N_NODES;
        float* s    = xs + N_NODES;
        float* u    = deg;
        const int TB = 256;
        const int gn = (N_NODES + TB - 1) / TB;
        const int ge = (N_EDGES + TB - 1) / TB;
        f_init <<<gn, TB, 0, stream>>>(deg);
        f_deg  <<<ge, TB, 0, stream>>>(dst, deg);
        f_node1<<<gn, TB, 0, stream>>>(x, deg, dinv, xs, s);
        f_sc1  <<<ge, TB, 0, stream>>>(src, dst, xs, dinv, s);
        f_node2<<<gn, TB, 0, stream>>>(s, dinv, W1, b1, W2, b2, u, out);
        f_sc2  <<<ge, TB, 0, stream>>>(src, dst, u, dinv, out);
    }
}